// Round 8
// baseline (1572.020 us; speedup 1.0000x reference)
//
#include <hip/hip_runtime.h>
#include <math.h>
#include <stdint.h>

#define NN 100000
#define NE 1600000
#define IN_DIM 128
#define HID 64
#define EDIM 16
#define NEG_SLOPE 0.2f

// ws layout (float offsets)
#define OFF_H    0          // NN*4
#define OFF_HS   400000     // NN
#define OFF_HD   500000     // NN
#define OFF_DEN  600000     // NN
#define OFF_XG   700000     // NN*4
#define OFF_P    1100000    // NE+NN  (ends at 2800000)
#define OFF_IMG  2800000    // 19*256 u32 = 4864

typedef __attribute__((ext_vector_type(8))) short bf16x8;
typedef __attribute__((ext_vector_type(4))) float f32x4;

#define MFMA16(A, B, C) __builtin_amdgcn_mfma_f32_16x16x32_bf16((A), (B), (C), 0, 0, 0)

__device__ inline bf16x8 as_bf(uint4 x) { union { uint4 a; bf16x8 b; } u; u.a = x; return u.b; }
__device__ inline f32x4 as_f4(uint4 x) { union { uint4 a; f32x4 f; } u; u.a = x; return u.f; }

// plain-C RNE float->bf16 pack (NO inline asm: keeps the VALU->MFMA hazard
// machinery fully compiler-visible; asm cvtpk feeding MFMA directly is the
// r6/r7 inf/NaN suspect)
__device__ inline uint16_t f2bf_rne(float f) {
    uint32_t x = __float_as_uint(f);
    uint32_t r = x + 0x7FFFu + ((x >> 16) & 1u);
    return (uint16_t)(r >> 16);
}
__device__ inline uint32_t pk2(float lo, float hi) {
    return (uint32_t)f2bf_rne(lo) | ((uint32_t)f2bf_rne(hi) << 16);
}

// ---------------- GAT conv (unchanged, passed r1-r5) ----------------
__global__ void node_kernel(const float* __restrict__ x, const float* __restrict__ Wg,
                            const float* __restrict__ a_src, const float* __restrict__ a_dst,
                            const float* __restrict__ b_gat,
                            float* __restrict__ h, float* __restrict__ hs,
                            float* __restrict__ hd, float* __restrict__ den,
                            float* __restrict__ xg) {
    int i = blockIdx.x * blockDim.x + threadIdx.x;
    if (i >= NN) return;
    float acc0 = 0.f, acc1 = 0.f, acc2 = 0.f, acc3 = 0.f;
    const float* xr = x + (size_t)i * IN_DIM;
#pragma unroll
    for (int d = 0; d < IN_DIM; d += 4) {
        float4 xv = *(const float4*)(xr + d);
        acc0 = fmaf(xv.x, Wg[(d + 0) * 4 + 0], acc0);
        acc1 = fmaf(xv.x, Wg[(d + 0) * 4 + 1], acc1);
        acc2 = fmaf(xv.x, Wg[(d + 0) * 4 + 2], acc2);
        acc3 = fmaf(xv.x, Wg[(d + 0) * 4 + 3], acc3);
        acc0 = fmaf(xv.y, Wg[(d + 1) * 4 + 0], acc0);
        acc1 = fmaf(xv.y, Wg[(d + 1) * 4 + 1], acc1);
        acc2 = fmaf(xv.y, Wg[(d + 1) * 4 + 2], acc2);
        acc3 = fmaf(xv.y, Wg[(d + 1) * 4 + 3], acc3);
        acc0 = fmaf(xv.z, Wg[(d + 2) * 4 + 0], acc0);
        acc1 = fmaf(xv.z, Wg[(d + 2) * 4 + 1], acc1);
        acc2 = fmaf(xv.z, Wg[(d + 2) * 4 + 2], acc2);
        acc3 = fmaf(xv.z, Wg[(d + 2) * 4 + 3], acc3);
        acc0 = fmaf(xv.w, Wg[(d + 3) * 4 + 0], acc0);
        acc1 = fmaf(xv.w, Wg[(d + 3) * 4 + 1], acc1);
        acc2 = fmaf(xv.w, Wg[(d + 3) * 4 + 2], acc2);
        acc3 = fmaf(xv.w, Wg[(d + 3) * 4 + 3], acc3);
    }
    *(float4*)(h + (size_t)i * 4) = make_float4(acc0, acc1, acc2, acc3);
    hs[i] = acc0 * a_src[0] + acc1 * a_src[1] + acc2 * a_src[2] + acc3 * a_src[3];
    hd[i] = acc0 * a_dst[0] + acc1 * a_dst[1] + acc2 * a_dst[2] + acc3 * a_dst[3];
    den[i] = 0.f;
    *(float4*)(xg + (size_t)i * 4) = make_float4(b_gat[0], b_gat[1], b_gat[2], b_gat[3]);
}

__global__ void att_kernel(const int* __restrict__ ei, const float* __restrict__ hs,
                           const float* __restrict__ hd, float* __restrict__ p,
                           float* __restrict__ den) {
    int e = blockIdx.x * blockDim.x + threadIdx.x;
    if (e >= NE + NN) return;
    int r, c;
    if (e < NE) { r = ei[e]; c = ei[NE + e]; }
    else { r = e - NE; c = r; }
    float v = hs[r] + hd[c];
    v = (v >= 0.f) ? v : NEG_SLOPE * v;
    float pe = expf(v);
    p[e] = pe;
    atomicAdd(&den[c], pe);
}

__global__ void agg_kernel(const int* __restrict__ ei, const float* __restrict__ h,
                           const float* __restrict__ p, const float* __restrict__ den,
                           float* __restrict__ xg) {
    int e = blockIdx.x * blockDim.x + threadIdx.x;
    if (e >= NE + NN) return;
    int r, c;
    if (e < NE) { r = ei[e]; c = ei[NE + e]; }
    else { r = e - NE; c = r; }
    float alpha = p[e] / den[c];
    float4 hv = *(const float4*)(h + (size_t)r * 4);
    atomicAdd(&xg[4 * c + 0], hv.x * alpha);
    atomicAdd(&xg[4 * c + 1], hv.y * alpha);
    atomicAdd(&xg[4 * c + 2], hv.z * alpha);
    atomicAdd(&xg[4 * c + 3], hv.w * alpha);
}

// ---------------- fragment image prep (PERMUTED layout, r6 design) ----------------
// Hidden-unit relabeling: D-slot (q, g, r) holds original unit
//   u(q,g,r) = 32*(q&1) + 8*g + 4*(q>>1) + r
// so slot value == k-position value for the NEXT layer's B operand:
// B fragment t word j <- accumulator q = 2*(j>=4) + t, reg r = j&3.
// => zero cross-lane movement between layers. W2/W3 K-dims identity; W1/W2
// M-dims and b2 permuted by u(); W3 M, b3 identity.
// Layer-1 B per lane g: j=0..3 -> y[4g+j]; j=4,5 -> f[2g],f[2g+1];
// j=6 (g==0 only) -> bias-one; j=7 -> zero.
__global__ void prep_kernel(const float* __restrict__ W1, const float* __restrict__ b1,
                            const float* __restrict__ W2, const float* __restrict__ b2,
                            const float* __restrict__ W3, const float* __restrict__ b3,
                            uint32_t* __restrict__ img) {
    int l = threadIdx.x;
    if (l >= 64) return;
    int e = l & 15, g = l >> 4;
    int er = e & 3, eq = e >> 2;
    // W1 fragments q=0..3 (i4 0..3)
    for (int q = 0; q < 4; ++q) {
        int u = 32 * (q & 1) + 8 * eq + 4 * (q >> 1) + er;
        img[q * 256 + l * 4 + 0] = pk2(W1[(8 + 4 * g + 0) * 64 + u], W1[(8 + 4 * g + 1) * 64 + u]);
        img[q * 256 + l * 4 + 1] = pk2(W1[(8 + 4 * g + 2) * 64 + u], W1[(8 + 4 * g + 3) * 64 + u]);
        img[q * 256 + l * 4 + 2] = pk2(W1[(2 * g + 0) * 64 + u], W1[(2 * g + 1) * 64 + u]);
        img[q * 256 + l * 4 + 3] = pk2((g == 0) ? b1[u] : 0.f, 0.f);
    }
    // W2 fragments (t,q) (i4 4..11): K identity, M permuted
    for (int t = 0; t < 2; ++t)
        for (int q = 0; q < 4; ++q) {
            int u = 32 * (q & 1) + 8 * eq + 4 * (q >> 1) + er;
            for (int j2 = 0; j2 < 4; ++j2) {
                int k0 = 32 * t + 8 * g + 2 * j2;
                img[(4 + t * 4 + q) * 256 + l * 4 + j2] =
                    pk2(W2[k0 * 64 + u], W2[(k0 + 1) * 64 + u]);
            }
        }
    // W3 fragments t (i4 12,13): K identity, M identity
    for (int t = 0; t < 2; ++t)
        for (int j2 = 0; j2 < 4; ++j2) {
            int k0 = 32 * t + 8 * g + 2 * j2;
            img[(12 + t) * 256 + l * 4 + j2] =
                pk2(W3[k0 * 16 + e], W3[(k0 + 1) * 16 + e]);
        }
    // b2 (i4 14..17): permuted by u(q,g,r)
    for (int q = 0; q < 4; ++q)
        for (int r = 0; r < 4; ++r)
            img[(14 + q) * 256 + l * 4 + r] =
                __float_as_uint(b2[32 * (q & 1) + 8 * g + 4 * (q >> 1) + r]);
    // b3 (i4 18)
    for (int r = 0; r < 4; ++r)
        img[18 * 256 + l * 4 + r] = __float_as_uint(b3[4 * g + r]);
}

// ---------------- RK4 edge MLP: MFMA, zero LDS, zero shuffles, ZERO ASM ----------------
__global__ __launch_bounds__(256, 3) void rk4_kernel(
    const int* __restrict__ ei, const float* __restrict__ ea,
    const float* __restrict__ xg, const uint32_t* __restrict__ img,
    float* __restrict__ out) {
    const int tid = threadIdx.x;
    const int w = tid >> 6, l = tid & 63;
    const int e = l & 15, g = l >> 4;
    const int edge = blockIdx.x * 64 + w * 16 + e;

    // weight/bias fragments (compiler parks these in the unified AGPR file)
    uint4 F[19];
#pragma unroll
    for (int i = 0; i < 19; ++i) F[i] = *(const uint4*)(img + i * 256 + l * 4);

    const bf16x8 W1f0 = as_bf(F[0]), W1f1 = as_bf(F[1]), W1f2 = as_bf(F[2]), W1f3 = as_bf(F[3]);
    const bf16x8 W2f00 = as_bf(F[4]), W2f01 = as_bf(F[5]), W2f02 = as_bf(F[6]), W2f03 = as_bf(F[7]);
    const bf16x8 W2f10 = as_bf(F[8]), W2f11 = as_bf(F[9]), W2f12 = as_bf(F[10]), W2f13 = as_bf(F[11]);
    const bf16x8 W3f0 = as_bf(F[12]), W3f1 = as_bf(F[13]);
    const f32x4 b2f0 = as_f4(F[14]), b2f1 = as_f4(F[15]), b2f2 = as_f4(F[16]), b2f3 = as_f4(F[17]);
    const f32x4 b3f = as_f4(F[18]);

    // per-lane static layer-1 B words: j=4,5 -> (f[2g], f[2g+1]); j=6 -> bias-one (g0)
    uint32_t Stf, Stb;
    {
        int idx = (g < 2) ? ei[edge] : ei[NE + edge];
        const float2 fv = *(const float2*)(xg + (size_t)idx * 4 + ((2 * g) & 3));
        Stf = pk2(fv.x, fv.y);
        Stb = (g == 0) ? 0x00003F80u : 0u;  // bf16(1.0) at k=6
    }

    float4 y4 = *(const float4*)(ea + (size_t)edge * 16 + 4 * g);
    float yv0 = y4.x, yv1 = y4.y, yv2 = y4.z, yv3 = y4.w;

    const f32x4 zero4 = {0.f, 0.f, 0.f, 0.f};
    const float dt6 = 0.125f / 6.0f;

    auto rhs = [&](float a0, float a1, float a2, float a3) -> f32x4 {
        uint4 bb;
        bb.x = pk2(a0, a1); bb.y = pk2(a2, a3); bb.z = Stf; bb.w = Stb;
        bf16x8 B1 = as_bf(bb);
        f32x4 h0 = MFMA16(W1f0, B1, zero4);
        f32x4 h1 = MFMA16(W1f1, B1, zero4);
        f32x4 h2 = MFMA16(W1f2, B1, zero4);
        f32x4 h3 = MFMA16(W1f3, B1, zero4);
        uint4 q20, q21;
        q20.x = pk2(fmaxf(h0[0], 0.f), fmaxf(h0[1], 0.f));
        q20.y = pk2(fmaxf(h0[2], 0.f), fmaxf(h0[3], 0.f));
        q20.z = pk2(fmaxf(h2[0], 0.f), fmaxf(h2[1], 0.f));
        q20.w = pk2(fmaxf(h2[2], 0.f), fmaxf(h2[3], 0.f));
        q21.x = pk2(fmaxf(h1[0], 0.f), fmaxf(h1[1], 0.f));
        q21.y = pk2(fmaxf(h1[2], 0.f), fmaxf(h1[3], 0.f));
        q21.z = pk2(fmaxf(h3[0], 0.f), fmaxf(h3[1], 0.f));
        q21.w = pk2(fmaxf(h3[2], 0.f), fmaxf(h3[3], 0.f));
        bf16x8 B20 = as_bf(q20), B21 = as_bf(q21);
        f32x4 p0 = MFMA16(W2f00, B20, b2f0); p0 = MFMA16(W2f10, B21, p0);
        f32x4 p1 = MFMA16(W2f01, B20, b2f1); p1 = MFMA16(W2f11, B21, p1);
        f32x4 p2 = MFMA16(W2f02, B20, b2f2); p2 = MFMA16(W2f12, B21, p2);
        f32x4 p3 = MFMA16(W2f03, B20, b2f3); p3 = MFMA16(W2f13, B21, p3);
        uint4 q30, q31;
        q30.x = pk2(fmaxf(p0[0], 0.f), fmaxf(p0[1], 0.f));
        q30.y = pk2(fmaxf(p0[2], 0.f), fmaxf(p0[3], 0.f));
        q30.z = pk2(fmaxf(p2[0], 0.f), fmaxf(p2[1], 0.f));
        q30.w = pk2(fmaxf(p2[2], 0.f), fmaxf(p2[3], 0.f));
        q31.x = pk2(fmaxf(p1[0], 0.f), fmaxf(p1[1], 0.f));
        q31.y = pk2(fmaxf(p1[2], 0.f), fmaxf(p1[3], 0.f));
        q31.z = pk2(fmaxf(p3[0], 0.f), fmaxf(p3[1], 0.f));
        q31.w = pk2(fmaxf(p3[2], 0.f), fmaxf(p3[3], 0.f));
        bf16x8 B30 = as_bf(q30), B31 = as_bf(q31);
        f32x4 kk = MFMA16(W3f0, B30, b3f);
        kk = MFMA16(W3f1, B31, kk);
        return kk;
    };

#pragma unroll 1
    for (int step = 0; step < 8; ++step) {
        float a0 = yv0, a1 = yv1, a2 = yv2, a3 = yv3;
        float c0 = 0.f, c1 = 0.f, c2 = 0.f, c3 = 0.f;
#pragma unroll 1
        for (int s = 0; s < 4; ++s) {
            f32x4 kk = rhs(a0, a1, a2, a3);
            float wk = (s == 1 || s == 2) ? 2.f : 1.f;
            float cs = (s < 2) ? 0.0625f : (s == 2) ? 0.125f : 0.f;
            c0 = fmaf(wk, kk[0], c0); c1 = fmaf(wk, kk[1], c1);
            c2 = fmaf(wk, kk[2], c2); c3 = fmaf(wk, kk[3], c3);
            a0 = fmaf(cs, kk[0], yv0); a1 = fmaf(cs, kk[1], yv1);
            a2 = fmaf(cs, kk[2], yv2); a3 = fmaf(cs, kk[3], yv3);
        }
        yv0 = fmaf(dt6, c0, yv0); yv1 = fmaf(dt6, c1, yv1);
        yv2 = fmaf(dt6, c2, yv2); yv3 = fmaf(dt6, c3, yv3);
    }

    *(float4*)(out + (size_t)edge * 16 + 4 * g) = make_float4(yv0, yv1, yv2, yv3);
}

extern "C" void kernel_launch(void* const* d_in, const int* in_sizes, int n_in,
                              void* d_out, int out_size, void* d_ws, size_t ws_size,
                              hipStream_t stream) {
    const float* x     = (const float*)d_in[0];
    const int*   ei    = (const int*)d_in[1];
    const float* ea    = (const float*)d_in[2];
    const float* Wg    = (const float*)d_in[3];
    const float* a_src = (const float*)d_in[4];
    const float* a_dst = (const float*)d_in[5];
    const float* b_gat = (const float*)d_in[6];
    const float* W1    = (const float*)d_in[7];
    const float* b1    = (const float*)d_in[8];
    const float* W2    = (const float*)d_in[9];
    const float* b2    = (const float*)d_in[10];
    const float* W3    = (const float*)d_in[11];
    const float* b3    = (const float*)d_in[12];

    float* ws  = (float*)d_ws;
    float* h   = ws + OFF_H;
    float* hs  = ws + OFF_HS;
    float* hd  = ws + OFF_HD;
    float* den = ws + OFF_DEN;
    float* xg  = ws + OFF_XG;
    float* p   = ws + OFF_P;
    uint32_t* img = (uint32_t*)(ws + OFF_IMG);

    prep_kernel<<<1, 64, 0, stream>>>(W1, b1, W2, b2, W3, b3, img);
    node_kernel<<<(NN + 255) / 256, 256, 0, stream>>>(x, Wg, a_src, a_dst, b_gat,
                                                      h, hs, hd, den, xg);
    int ne_tot = NE + NN;
    att_kernel<<<(ne_tot + 255) / 256, 256, 0, stream>>>(ei, hs, hd, p, den);
    agg_kernel<<<(ne_tot + 255) / 256, 256, 0, stream>>>(ei, h, p, den, xg);
    rk4_kernel<<<NE / 64, 256, 0, stream>>>(ei, ea, xg, img, (float*)d_out);
}

// Round 9
// 1382.276 us; speedup vs baseline: 1.1373x; 1.1373x over previous
//
#include <hip/hip_runtime.h>
#include <hip/hip_bf16.h>
#include <math.h>
#include <stdint.h>

#define NN 100000
#define NE 1600000
#define IN_DIM 128
#define HID 64
#define EDIM 16
#define NEG_SLOPE 0.2f

// ws layout (float offsets)
#define OFF_H    0          // NN*4
#define OFF_HS   400000     // NN
#define OFF_HD   500000     // NN
#define OFF_DEN  600000     // NN
#define OFF_XG   700000     // NN*4
#define OFF_IMG  2800000    // 19*256 u32 = 4864

typedef __attribute__((ext_vector_type(8))) short bf16x8;
typedef __attribute__((ext_vector_type(4))) float f32x4;

#define MFMA16(A, B, C) __builtin_amdgcn_mfma_f32_16x16x32_bf16((A), (B), (C), 0, 0, 0)

__device__ inline bf16x8 as_bf(uint4 x) { union { uint4 a; bf16x8 b; } u; u.a = x; return u.b; }
__device__ inline f32x4 as_f4(uint4 x) { union { uint4 a; f32x4 f; } u; u.a = x; return u.f; }

// compiler-native RNE f32x2 -> packed bf16x2 (NO inline asm: hazards stay
// compiler-visible — asm cvtpk feeding MFMA was the r6/r7 inf/NaN; the
// bit-twiddle fallback (r8) was correct but ~7 VALU/value)
__device__ inline uint32_t pk2(float lo, float hi) {
    __hip_bfloat162 h2 = __float22bfloat162_rn(make_float2(lo, hi));
    union { __hip_bfloat162 h; uint32_t u; } uu; uu.h = h2; return uu.u;
}

// prep-side RNE pack (cold path, keep the proven bit version)
__device__ inline uint16_t f2bf_rne(float f) {
    uint32_t x = __float_as_uint(f);
    uint32_t r = x + 0x7FFFu + ((x >> 16) & 1u);
    return (uint16_t)(r >> 16);
}
__device__ inline uint32_t pk2c(float lo, float hi) {
    return (uint32_t)f2bf_rne(lo) | ((uint32_t)f2bf_rne(hi) << 16);
}

// ---------------- GAT conv ----------------
__global__ void node_kernel(const float* __restrict__ x, const float* __restrict__ Wg,
                            const float* __restrict__ a_src, const float* __restrict__ a_dst,
                            float* __restrict__ h, float* __restrict__ hs,
                            float* __restrict__ hd, float* __restrict__ den,
                            float* __restrict__ xg) {
    int i = blockIdx.x * blockDim.x + threadIdx.x;
    if (i >= NN) return;
    float acc0 = 0.f, acc1 = 0.f, acc2 = 0.f, acc3 = 0.f;
    const float* xr = x + (size_t)i * IN_DIM;
#pragma unroll
    for (int d = 0; d < IN_DIM; d += 4) {
        float4 xv = *(const float4*)(xr + d);
        acc0 = fmaf(xv.x, Wg[(d + 0) * 4 + 0], acc0);
        acc1 = fmaf(xv.x, Wg[(d + 0) * 4 + 1], acc1);
        acc2 = fmaf(xv.x, Wg[(d + 0) * 4 + 2], acc2);
        acc3 = fmaf(xv.x, Wg[(d + 0) * 4 + 3], acc3);
        acc0 = fmaf(xv.y, Wg[(d + 1) * 4 + 0], acc0);
        acc1 = fmaf(xv.y, Wg[(d + 1) * 4 + 1], acc1);
        acc2 = fmaf(xv.y, Wg[(d + 1) * 4 + 2], acc2);
        acc3 = fmaf(xv.y, Wg[(d + 1) * 4 + 3], acc3);
        acc0 = fmaf(xv.z, Wg[(d + 2) * 4 + 0], acc0);
        acc1 = fmaf(xv.z, Wg[(d + 2) * 4 + 1], acc1);
        acc2 = fmaf(xv.z, Wg[(d + 2) * 4 + 2], acc2);
        acc3 = fmaf(xv.z, Wg[(d + 2) * 4 + 3], acc3);
        acc0 = fmaf(xv.w, Wg[(d + 3) * 4 + 0], acc0);
        acc1 = fmaf(xv.w, Wg[(d + 3) * 4 + 1], acc1);
        acc2 = fmaf(xv.w, Wg[(d + 3) * 4 + 2], acc2);
        acc3 = fmaf(xv.w, Wg[(d + 3) * 4 + 3], acc3);
    }
    *(float4*)(h + (size_t)i * 4) = make_float4(acc0, acc1, acc2, acc3);
    hs[i] = acc0 * a_src[0] + acc1 * a_src[1] + acc2 * a_src[2] + acc3 * a_src[3];
    hd[i] = acc0 * a_dst[0] + acc1 * a_dst[1] + acc2 * a_dst[2] + acc3 * a_dst[3];
    den[i] = 0.f;
    *(float4*)(xg + (size_t)i * 4) = make_float4(0.f, 0.f, 0.f, 0.f);
}

// fused attention numerator+denominator accumulation (one edge pass; p buffer
// eliminated — alpha division deferred to div_kernel, algebraically identical)
__global__ void edge_kernel(const int* __restrict__ ei, const float* __restrict__ hs,
                            const float* __restrict__ hd, const float* __restrict__ h,
                            float* __restrict__ den, float* __restrict__ xg) {
    int e = blockIdx.x * blockDim.x + threadIdx.x;
    if (e >= NE + NN) return;
    int r, c;
    if (e < NE) { r = ei[e]; c = ei[NE + e]; }
    else { r = e - NE; c = r; }
    float v = hs[r] + hd[c];
    v = (v >= 0.f) ? v : NEG_SLOPE * v;
    float pe = expf(v);
    float4 hv = *(const float4*)(h + (size_t)r * 4);
    atomicAdd(&den[c], pe);
    atomicAdd(&xg[4 * c + 0], pe * hv.x);
    atomicAdd(&xg[4 * c + 1], pe * hv.y);
    atomicAdd(&xg[4 * c + 2], pe * hv.z);
    atomicAdd(&xg[4 * c + 3], pe * hv.w);
}

__global__ void div_kernel(float* __restrict__ xg, const float* __restrict__ den,
                           const float* __restrict__ b_gat) {
    int i = blockIdx.x * blockDim.x + threadIdx.x;
    if (i >= NN) return;
    float inv = 1.0f / den[i];
    float4 n = *(const float4*)(xg + (size_t)i * 4);
    *(float4*)(xg + (size_t)i * 4) =
        make_float4(fmaf(n.x, inv, b_gat[0]), fmaf(n.y, inv, b_gat[1]),
                    fmaf(n.z, inv, b_gat[2]), fmaf(n.w, inv, b_gat[3]));
}

// ---------------- fragment image prep (PERMUTED layout, validated r8) ----------------
// Hidden-unit relabeling: D-slot (q, g, r) holds original unit
//   u(q,g,r) = 32*(q&1) + 8*g + 4*(q>>1) + r
// so slot value == k-position value for the NEXT layer's B operand => zero
// cross-lane movement between layers. W2/W3 K-dims identity; W1/W2 M-dims and
// b2 permuted by u(); W3 M, b3 identity.
// Layer-1 B per lane g: j=0..3 -> y[4g+j]; j=4,5 -> f[2g],f[2g+1];
// j=6 (g==0 only) -> bias-one; j=7 -> zero.
__global__ void prep_kernel(const float* __restrict__ W1, const float* __restrict__ b1,
                            const float* __restrict__ W2, const float* __restrict__ b2,
                            const float* __restrict__ W3, const float* __restrict__ b3,
                            uint32_t* __restrict__ img) {
    int l = threadIdx.x;
    if (l >= 64) return;
    int e = l & 15, g = l >> 4;
    int er = e & 3, eq = e >> 2;
    for (int q = 0; q < 4; ++q) {
        int u = 32 * (q & 1) + 8 * eq + 4 * (q >> 1) + er;
        img[q * 256 + l * 4 + 0] = pk2c(W1[(8 + 4 * g + 0) * 64 + u], W1[(8 + 4 * g + 1) * 64 + u]);
        img[q * 256 + l * 4 + 1] = pk2c(W1[(8 + 4 * g + 2) * 64 + u], W1[(8 + 4 * g + 3) * 64 + u]);
        img[q * 256 + l * 4 + 2] = pk2c(W1[(2 * g + 0) * 64 + u], W1[(2 * g + 1) * 64 + u]);
        img[q * 256 + l * 4 + 3] = pk2c((g == 0) ? b1[u] : 0.f, 0.f);
    }
    for (int t = 0; t < 2; ++t)
        for (int q = 0; q < 4; ++q) {
            int u = 32 * (q & 1) + 8 * eq + 4 * (q >> 1) + er;
            for (int j2 = 0; j2 < 4; ++j2) {
                int k0 = 32 * t + 8 * g + 2 * j2;
                img[(4 + t * 4 + q) * 256 + l * 4 + j2] =
                    pk2c(W2[k0 * 64 + u], W2[(k0 + 1) * 64 + u]);
            }
        }
    for (int t = 0; t < 2; ++t)
        for (int j2 = 0; j2 < 4; ++j2) {
            int k0 = 32 * t + 8 * g + 2 * j2;
            img[(12 + t) * 256 + l * 4 + j2] =
                pk2c(W3[k0 * 16 + e], W3[(k0 + 1) * 16 + e]);
        }
    for (int q = 0; q < 4; ++q)
        for (int r = 0; r < 4; ++r)
            img[(14 + q) * 256 + l * 4 + r] =
                __float_as_uint(b2[32 * (q & 1) + 8 * g + 4 * (q >> 1) + r]);
    for (int r = 0; r < 4; ++r)
        img[18 * 256 + l * 4 + r] = __float_as_uint(b3[4 * g + r]);
}

// ---------------- RK4 edge MLP: MFMA, zero LDS, zero shuffles, zero asm ----------------
__global__ __launch_bounds__(256, 3) void rk4_kernel(
    const int* __restrict__ ei, const float* __restrict__ ea,
    const float* __restrict__ xg, const uint32_t* __restrict__ img,
    float* __restrict__ out) {
    const int tid = threadIdx.x;
    const int w = tid >> 6, l = tid & 63;
    const int e = l & 15, g = l >> 4;
    const int edge = blockIdx.x * 64 + w * 16 + e;

    uint4 F[19];
#pragma unroll
    for (int i = 0; i < 19; ++i) F[i] = *(const uint4*)(img + i * 256 + l * 4);

    const bf16x8 W1f0 = as_bf(F[0]), W1f1 = as_bf(F[1]), W1f2 = as_bf(F[2]), W1f3 = as_bf(F[3]);
    const bf16x8 W2f00 = as_bf(F[4]), W2f01 = as_bf(F[5]), W2f02 = as_bf(F[6]), W2f03 = as_bf(F[7]);
    const bf16x8 W2f10 = as_bf(F[8]), W2f11 = as_bf(F[9]), W2f12 = as_bf(F[10]), W2f13 = as_bf(F[11]);
    const bf16x8 W3f0 = as_bf(F[12]), W3f1 = as_bf(F[13]);
    const f32x4 b2f0 = as_f4(F[14]), b2f1 = as_f4(F[15]), b2f2 = as_f4(F[16]), b2f3 = as_f4(F[17]);
    const f32x4 b3f = as_f4(F[18]);

    uint32_t Stf, Stb;
    {
        int idx = (g < 2) ? ei[edge] : ei[NE + edge];
        const float2 fv = *(const float2*)(xg + (size_t)idx * 4 + ((2 * g) & 3));
        Stf = pk2(fv.x, fv.y);
        Stb = (g == 0) ? 0x00003F80u : 0u;  // bf16(1.0) at k=6
    }

    float4 y4 = *(const float4*)(ea + (size_t)edge * 16 + 4 * g);
    float yv0 = y4.x, yv1 = y4.y, yv2 = y4.z, yv3 = y4.w;

    const f32x4 zero4 = {0.f, 0.f, 0.f, 0.f};
    const float dt6 = 0.125f / 6.0f;

    auto rhs = [&](float a0, float a1, float a2, float a3) -> f32x4 {
        uint4 bb;
        bb.x = pk2(a0, a1); bb.y = pk2(a2, a3); bb.z = Stf; bb.w = Stb;
        bf16x8 B1 = as_bf(bb);
        f32x4 h0 = MFMA16(W1f0, B1, zero4);
        f32x4 h1 = MFMA16(W1f1, B1, zero4);
        f32x4 h2 = MFMA16(W1f2, B1, zero4);
        f32x4 h3 = MFMA16(W1f3, B1, zero4);
        uint4 q20, q21;
        q20.x = pk2(fmaxf(h0[0], 0.f), fmaxf(h0[1], 0.f));
        q20.y = pk2(fmaxf(h0[2], 0.f), fmaxf(h0[3], 0.f));
        q20.z = pk2(fmaxf(h2[0], 0.f), fmaxf(h2[1], 0.f));
        q20.w = pk2(fmaxf(h2[2], 0.f), fmaxf(h2[3], 0.f));
        q21.x = pk2(fmaxf(h1[0], 0.f), fmaxf(h1[1], 0.f));
        q21.y = pk2(fmaxf(h1[2], 0.f), fmaxf(h1[3], 0.f));
        q21.z = pk2(fmaxf(h3[0], 0.f), fmaxf(h3[1], 0.f));
        q21.w = pk2(fmaxf(h3[2], 0.f), fmaxf(h3[3], 0.f));
        bf16x8 B20 = as_bf(q20), B21 = as_bf(q21);
        f32x4 p0 = MFMA16(W2f00, B20, b2f0); p0 = MFMA16(W2f10, B21, p0);
        f32x4 p1 = MFMA16(W2f01, B20, b2f1); p1 = MFMA16(W2f11, B21, p1);
        f32x4 p2 = MFMA16(W2f02, B20, b2f2); p2 = MFMA16(W2f12, B21, p2);
        f32x4 p3 = MFMA16(W2f03, B20, b2f3); p3 = MFMA16(W2f13, B21, p3);
        uint4 q30, q31;
        q30.x = pk2(fmaxf(p0[0], 0.f), fmaxf(p0[1], 0.f));
        q30.y = pk2(fmaxf(p0[2], 0.f), fmaxf(p0[3], 0.f));
        q30.z = pk2(fmaxf(p2[0], 0.f), fmaxf(p2[1], 0.f));
        q30.w = pk2(fmaxf(p2[2], 0.f), fmaxf(p2[3], 0.f));
        q31.x = pk2(fmaxf(p1[0], 0.f), fmaxf(p1[1], 0.f));
        q31.y = pk2(fmaxf(p1[2], 0.f), fmaxf(p1[3], 0.f));
        q31.z = pk2(fmaxf(p3[0], 0.f), fmaxf(p3[1], 0.f));
        q31.w = pk2(fmaxf(p3[2], 0.f), fmaxf(p3[3], 0.f));
        bf16x8 B30 = as_bf(q30), B31 = as_bf(q31);
        f32x4 kk = MFMA16(W3f0, B30, b3f);
        kk = MFMA16(W3f1, B31, kk);
        return kk;
    };

#pragma unroll 1
    for (int step = 0; step < 8; ++step) {
        float a0 = yv0, a1 = yv1, a2 = yv2, a3 = yv3;
        float c0 = 0.f, c1 = 0.f, c2 = 0.f, c3 = 0.f;
#pragma unroll 1
        for (int s = 0; s < 4; ++s) {
            f32x4 kk = rhs(a0, a1, a2, a3);
            float wk = (s == 1 || s == 2) ? 2.f : 1.f;
            float cs = (s < 2) ? 0.0625f : (s == 2) ? 0.125f : 0.f;
            c0 = fmaf(wk, kk[0], c0); c1 = fmaf(wk, kk[1], c1);
            c2 = fmaf(wk, kk[2], c2); c3 = fmaf(wk, kk[3], c3);
            a0 = fmaf(cs, kk[0], yv0); a1 = fmaf(cs, kk[1], yv1);
            a2 = fmaf(cs, kk[2], yv2); a3 = fmaf(cs, kk[3], yv3);
        }
        yv0 = fmaf(dt6, c0, yv0); yv1 = fmaf(dt6, c1, yv1);
        yv2 = fmaf(dt6, c2, yv2); yv3 = fmaf(dt6, c3, yv3);
    }

    *(float4*)(out + (size_t)edge * 16 + 4 * g) = make_float4(yv0, yv1, yv2, yv3);
}

extern "C" void kernel_launch(void* const* d_in, const int* in_sizes, int n_in,
                              void* d_out, int out_size, void* d_ws, size_t ws_size,
                              hipStream_t stream) {
    const float* x     = (const float*)d_in[0];
    const int*   ei    = (const int*)d_in[1];
    const float* ea    = (const float*)d_in[2];
    const float* Wg    = (const float*)d_in[3];
    const float* a_src = (const float*)d_in[4];
    const float* a_dst = (const float*)d_in[5];
    const float* b_gat = (const float*)d_in[6];
    const float* W1    = (const float*)d_in[7];
    const float* b1    = (const float*)d_in[8];
    const float* W2    = (const float*)d_in[9];
    const float* b2    = (const float*)d_in[10];
    const float* W3    = (const float*)d_in[11];
    const float* b3    = (const float*)d_in[12];

    float* ws  = (float*)d_ws;
    float* h   = ws + OFF_H;
    float* hs  = ws + OFF_HS;
    float* hd  = ws + OFF_HD;
    float* den = ws + OFF_DEN;
    float* xg  = ws + OFF_XG;
    uint32_t* img = (uint32_t*)(ws + OFF_IMG);

    prep_kernel<<<1, 64, 0, stream>>>(W1, b1, W2, b2, W3, b3, img);
    node_kernel<<<(NN + 255) / 256, 256, 0, stream>>>(x, Wg, a_src, a_dst,
                                                      h, hs, hd, den, xg);
    int ne_tot = NE + NN;
    edge_kernel<<<(ne_tot + 255) / 256, 256, 0, stream>>>(ei, hs, hd, h, den, xg);
    div_kernel<<<(NN + 255) / 256, 256, 0, stream>>>(xg, den, b_gat);
    rk4_kernel<<<NE / 64, 256, 0, stream>>>(ei, ea, xg, img, (float*)d_out);
}

// Round 10
// 1111.306 us; speedup vs baseline: 1.4146x; 1.2438x over previous
//
#include <hip/hip_runtime.h>
#include <math.h>
#include <stdint.h>

#define NN 100000
#define NE 1600000
#define IN_DIM 128
#define HID 64
#define EDIM 16
#define NEG_SLOPE 0.2f

// ws layout (float offsets)
#define OFF_H    0          // NN*4
#define OFF_HS   400000     // NN
#define OFF_HD   500000     // NN
#define OFF_DEN  600000     // NN
#define OFF_XG   700000     // NN*4
#define OFF_IMG  2800000    // 19*256 u32 = 4864

typedef __attribute__((ext_vector_type(8))) short bf16x8;
typedef __attribute__((ext_vector_type(4))) float f32x4;
typedef __attribute__((ext_vector_type(2))) float f32x2;
typedef __attribute__((ext_vector_type(2))) __bf16 bf16x2;

#define MFMA16(A, B, C) __builtin_amdgcn_mfma_f32_16x16x32_bf16((A), (B), (C), 0, 0, 0)

__device__ inline bf16x8 as_bf(uint4 x) { union { uint4 a; bf16x8 b; } u; u.a = x; return u.b; }
__device__ inline f32x4 as_f4(uint4 x) { union { uint4 a; f32x4 f; } u; u.a = x; return u.f; }

// NATIVE packed f32x2 -> bf16x2 via LLVM fptrunc (lowers to v_cvt_pk_bf16_f32
// on gfx950, RNE). Compiler-generated => VALU->MFMA hazards handled (unlike the
// r6/r7 asm blob). r9's __float22bfloat162_rn was a ~12-op software path.
__device__ inline uint32_t pk2(float lo, float hi) {
    f32x2 v; v.x = lo; v.y = hi;
    bf16x2 b = __builtin_convertvector(v, bf16x2);
    union { bf16x2 b; uint32_t u; } uu; uu.b = b; return uu.u;
}

// prep-side RNE pack (cold path, proven bit version)
__device__ inline uint16_t f2bf_rne(float f) {
    uint32_t x = __float_as_uint(f);
    uint32_t r = x + 0x7FFFu + ((x >> 16) & 1u);
    return (uint16_t)(r >> 16);
}
__device__ inline uint32_t pk2c(float lo, float hi) {
    return (uint32_t)f2bf_rne(lo) | ((uint32_t)f2bf_rne(hi) << 16);
}

// ---------------- GAT conv ----------------
__global__ void node_kernel(const float* __restrict__ x, const float* __restrict__ Wg,
                            const float* __restrict__ a_src, const float* __restrict__ a_dst,
                            float* __restrict__ h, float* __restrict__ hs,
                            float* __restrict__ hd, float* __restrict__ den,
                            float* __restrict__ xg) {
    int i = blockIdx.x * blockDim.x + threadIdx.x;
    if (i >= NN) return;
    float acc0 = 0.f, acc1 = 0.f, acc2 = 0.f, acc3 = 0.f;
    const float* xr = x + (size_t)i * IN_DIM;
#pragma unroll
    for (int d = 0; d < IN_DIM; d += 4) {
        float4 xv = *(const float4*)(xr + d);
        acc0 = fmaf(xv.x, Wg[(d + 0) * 4 + 0], acc0);
        acc1 = fmaf(xv.x, Wg[(d + 0) * 4 + 1], acc1);
        acc2 = fmaf(xv.x, Wg[(d + 0) * 4 + 2], acc2);
        acc3 = fmaf(xv.x, Wg[(d + 0) * 4 + 3], acc3);
        acc0 = fmaf(xv.y, Wg[(d + 1) * 4 + 0], acc0);
        acc1 = fmaf(xv.y, Wg[(d + 1) * 4 + 1], acc1);
        acc2 = fmaf(xv.y, Wg[(d + 1) * 4 + 2], acc2);
        acc3 = fmaf(xv.y, Wg[(d + 1) * 4 + 3], acc3);
        acc0 = fmaf(xv.z, Wg[(d + 2) * 4 + 0], acc0);
        acc1 = fmaf(xv.z, Wg[(d + 2) * 4 + 1], acc1);
        acc2 = fmaf(xv.z, Wg[(d + 2) * 4 + 2], acc2);
        acc3 = fmaf(xv.z, Wg[(d + 2) * 4 + 3], acc3);
        acc0 = fmaf(xv.w, Wg[(d + 3) * 4 + 0], acc0);
        acc1 = fmaf(xv.w, Wg[(d + 3) * 4 + 1], acc1);
        acc2 = fmaf(xv.w, Wg[(d + 3) * 4 + 2], acc2);
        acc3 = fmaf(xv.w, Wg[(d + 3) * 4 + 3], acc3);
    }
    *(float4*)(h + (size_t)i * 4) = make_float4(acc0, acc1, acc2, acc3);
    hs[i] = acc0 * a_src[0] + acc1 * a_src[1] + acc2 * a_src[2] + acc3 * a_src[3];
    hd[i] = acc0 * a_dst[0] + acc1 * a_dst[1] + acc2 * a_dst[2] + acc3 * a_dst[3];
    den[i] = 0.f;
    *(float4*)(xg + (size_t)i * 4) = make_float4(0.f, 0.f, 0.f, 0.f);
}

// fused attention numerator+denominator accumulation (validated r9)
__global__ void edge_kernel(const int* __restrict__ ei, const float* __restrict__ hs,
                            const float* __restrict__ hd, const float* __restrict__ h,
                            float* __restrict__ den, float* __restrict__ xg) {
    int e = blockIdx.x * blockDim.x + threadIdx.x;
    if (e >= NE + NN) return;
    int r, c;
    if (e < NE) { r = ei[e]; c = ei[NE + e]; }
    else { r = e - NE; c = r; }
    float v = hs[r] + hd[c];
    v = (v >= 0.f) ? v : NEG_SLOPE * v;
    float pe = expf(v);
    float4 hv = *(const float4*)(h + (size_t)r * 4);
    atomicAdd(&den[c], pe);
    atomicAdd(&xg[4 * c + 0], pe * hv.x);
    atomicAdd(&xg[4 * c + 1], pe * hv.y);
    atomicAdd(&xg[4 * c + 2], pe * hv.z);
    atomicAdd(&xg[4 * c + 3], pe * hv.w);
}

__global__ void div_kernel(float* __restrict__ xg, const float* __restrict__ den,
                           const float* __restrict__ b_gat) {
    int i = blockIdx.x * blockDim.x + threadIdx.x;
    if (i >= NN) return;
    float inv = 1.0f / den[i];
    float4 n = *(const float4*)(xg + (size_t)i * 4);
    *(float4*)(xg + (size_t)i * 4) =
        make_float4(fmaf(n.x, inv, b_gat[0]), fmaf(n.y, inv, b_gat[1]),
                    fmaf(n.z, inv, b_gat[2]), fmaf(n.w, inv, b_gat[3]));
}

// ---------------- fragment image prep (PERMUTED layout, validated r8/r9) ----------------
// Hidden-unit relabeling: D-slot (q, g, r) holds original unit
//   u(q,g,r) = 32*(q&1) + 8*g + 4*(q>>1) + r
// so slot value == k-position value for the NEXT layer's B operand => zero
// cross-lane movement between layers. W2/W3 K-dims identity; W1/W2 M-dims and
// b2 permuted by u(); W3 M, b3 identity.
// Layer-1 B per lane g: j=0..3 -> y[4g+j]; j=4,5 -> f[2g],f[2g+1];
// j=6 (g==0 only) -> bias-one; j=7 -> zero.
__global__ void prep_kernel(const float* __restrict__ W1, const float* __restrict__ b1,
                            const float* __restrict__ W2, const float* __restrict__ b2,
                            const float* __restrict__ W3, const float* __restrict__ b3,
                            uint32_t* __restrict__ img) {
    int l = threadIdx.x;
    if (l >= 64) return;
    int e = l & 15, g = l >> 4;
    int er = e & 3, eq = e >> 2;
    for (int q = 0; q < 4; ++q) {
        int u = 32 * (q & 1) + 8 * eq + 4 * (q >> 1) + er;
        img[q * 256 + l * 4 + 0] = pk2c(W1[(8 + 4 * g + 0) * 64 + u], W1[(8 + 4 * g + 1) * 64 + u]);
        img[q * 256 + l * 4 + 1] = pk2c(W1[(8 + 4 * g + 2) * 64 + u], W1[(8 + 4 * g + 3) * 64 + u]);
        img[q * 256 + l * 4 + 2] = pk2c(W1[(2 * g + 0) * 64 + u], W1[(2 * g + 1) * 64 + u]);
        img[q * 256 + l * 4 + 3] = pk2c((g == 0) ? b1[u] : 0.f, 0.f);
    }
    for (int t = 0; t < 2; ++t)
        for (int q = 0; q < 4; ++q) {
            int u = 32 * (q & 1) + 8 * eq + 4 * (q >> 1) + er;
            for (int j2 = 0; j2 < 4; ++j2) {
                int k0 = 32 * t + 8 * g + 2 * j2;
                img[(4 + t * 4 + q) * 256 + l * 4 + j2] =
                    pk2c(W2[k0 * 64 + u], W2[(k0 + 1) * 64 + u]);
            }
        }
    for (int t = 0; t < 2; ++t)
        for (int j2 = 0; j2 < 4; ++j2) {
            int k0 = 32 * t + 8 * g + 2 * j2;
            img[(12 + t) * 256 + l * 4 + j2] =
                pk2c(W3[k0 * 16 + e], W3[(k0 + 1) * 16 + e]);
        }
    for (int q = 0; q < 4; ++q)
        for (int r = 0; r < 4; ++r)
            img[(14 + q) * 256 + l * 4 + r] =
                __float_as_uint(b2[32 * (q & 1) + 8 * g + 4 * (q >> 1) + r]);
    for (int r = 0; r < 4; ++r)
        img[18 * 256 + l * 4 + r] = __float_as_uint(b3[4 * g + r]);
}

// ---------------- RK4 edge MLP: MFMA, zero LDS, zero shuffles, zero asm ----------------
__global__ __launch_bounds__(256, 3) void rk4_kernel(
    const int* __restrict__ ei, const float* __restrict__ ea,
    const float* __restrict__ xg, const uint32_t* __restrict__ img,
    float* __restrict__ out) {
    const int tid = threadIdx.x;
    const int w = tid >> 6, l = tid & 63;
    const int e = l & 15, g = l >> 4;
    const int edge = blockIdx.x * 64 + w * 16 + e;

    uint4 F[19];
#pragma unroll
    for (int i = 0; i < 19; ++i) F[i] = *(const uint4*)(img + i * 256 + l * 4);

    const bf16x8 W1f0 = as_bf(F[0]), W1f1 = as_bf(F[1]), W1f2 = as_bf(F[2]), W1f3 = as_bf(F[3]);
    const bf16x8 W2f00 = as_bf(F[4]), W2f01 = as_bf(F[5]), W2f02 = as_bf(F[6]), W2f03 = as_bf(F[7]);
    const bf16x8 W2f10 = as_bf(F[8]), W2f11 = as_bf(F[9]), W2f12 = as_bf(F[10]), W2f13 = as_bf(F[11]);
    const bf16x8 W3f0 = as_bf(F[12]), W3f1 = as_bf(F[13]);
    const f32x4 b2f0 = as_f4(F[14]), b2f1 = as_f4(F[15]), b2f2 = as_f4(F[16]), b2f3 = as_f4(F[17]);
    const f32x4 b3f = as_f4(F[18]);

    uint32_t Stf, Stb;
    {
        int idx = (g < 2) ? ei[edge] : ei[NE + edge];
        const float2 fv = *(const float2*)(xg + (size_t)idx * 4 + ((2 * g) & 3));
        Stf = pk2(fv.x, fv.y);
        Stb = (g == 0) ? 0x00003F80u : 0u;  // bf16(1.0) at k=6
    }

    float4 y4 = *(const float4*)(ea + (size_t)edge * 16 + 4 * g);
    float yv0 = y4.x, yv1 = y4.y, yv2 = y4.z, yv3 = y4.w;

    const f32x4 zero4 = {0.f, 0.f, 0.f, 0.f};
    const float dt6 = 0.125f / 6.0f;

    auto rhs = [&](float a0, float a1, float a2, float a3) -> f32x4 {
        uint4 bb;
        bb.x = pk2(a0, a1); bb.y = pk2(a2, a3); bb.z = Stf; bb.w = Stb;
        bf16x8 B1 = as_bf(bb);
        f32x4 h0 = MFMA16(W1f0, B1, zero4);
        f32x4 h1 = MFMA16(W1f1, B1, zero4);
        f32x4 h2 = MFMA16(W1f2, B1, zero4);
        f32x4 h3 = MFMA16(W1f3, B1, zero4);
        uint4 q20, q21;
        q20.x = pk2(fmaxf(h0[0], 0.f), fmaxf(h0[1], 0.f));
        q20.y = pk2(fmaxf(h0[2], 0.f), fmaxf(h0[3], 0.f));
        q20.z = pk2(fmaxf(h2[0], 0.f), fmaxf(h2[1], 0.f));
        q20.w = pk2(fmaxf(h2[2], 0.f), fmaxf(h2[3], 0.f));
        q21.x = pk2(fmaxf(h1[0], 0.f), fmaxf(h1[1], 0.f));
        q21.y = pk2(fmaxf(h1[2], 0.f), fmaxf(h1[3], 0.f));
        q21.z = pk2(fmaxf(h3[0], 0.f), fmaxf(h3[1], 0.f));
        q21.w = pk2(fmaxf(h3[2], 0.f), fmaxf(h3[3], 0.f));
        bf16x8 B20 = as_bf(q20), B21 = as_bf(q21);
        f32x4 p0 = MFMA16(W2f00, B20, b2f0); p0 = MFMA16(W2f10, B21, p0);
        f32x4 p1 = MFMA16(W2f01, B20, b2f1); p1 = MFMA16(W2f11, B21, p1);
        f32x4 p2 = MFMA16(W2f02, B20, b2f2); p2 = MFMA16(W2f12, B21, p2);
        f32x4 p3 = MFMA16(W2f03, B20, b2f3); p3 = MFMA16(W2f13, B21, p3);
        uint4 q30, q31;
        q30.x = pk2(fmaxf(p0[0], 0.f), fmaxf(p0[1], 0.f));
        q30.y = pk2(fmaxf(p0[2], 0.f), fmaxf(p0[3], 0.f));
        q30.z = pk2(fmaxf(p2[0], 0.f), fmaxf(p2[1], 0.f));
        q30.w = pk2(fmaxf(p2[2], 0.f), fmaxf(p2[3], 0.f));
        q31.x = pk2(fmaxf(p1[0], 0.f), fmaxf(p1[1], 0.f));
        q31.y = pk2(fmaxf(p1[2], 0.f), fmaxf(p1[3], 0.f));
        q31.z = pk2(fmaxf(p3[0], 0.f), fmaxf(p3[1], 0.f));
        q31.w = pk2(fmaxf(p3[2], 0.f), fmaxf(p3[3], 0.f));
        bf16x8 B30 = as_bf(q30), B31 = as_bf(q31);
        f32x4 kk = MFMA16(W3f0, B30, b3f);
        kk = MFMA16(W3f1, B31, kk);
        return kk;
    };

#pragma unroll 1
    for (int step = 0; step < 8; ++step) {
        float a0 = yv0, a1 = yv1, a2 = yv2, a3 = yv3;
        float c0 = 0.f, c1 = 0.f, c2 = 0.f, c3 = 0.f;
#pragma unroll 1
        for (int s = 0; s < 4; ++s) {
            f32x4 kk = rhs(a0, a1, a2, a3);
            float wk = (s == 1 || s == 2) ? 2.f : 1.f;
            float cs = (s < 2) ? 0.0625f : (s == 2) ? 0.125f : 0.f;
            c0 = fmaf(wk, kk[0], c0); c1 = fmaf(wk, kk[1], c1);
            c2 = fmaf(wk, kk[2], c2); c3 = fmaf(wk, kk[3], c3);
            a0 = fmaf(cs, kk[0], yv0); a1 = fmaf(cs, kk[1], yv1);
            a2 = fmaf(cs, kk[2], yv2); a3 = fmaf(cs, kk[3], yv3);
        }
        yv0 = fmaf(dt6, c0, yv0); yv1 = fmaf(dt6, c1, yv1);
        yv2 = fmaf(dt6, c2, yv2); yv3 = fmaf(dt6, c3, yv3);
    }

    *(float4*)(out + (size_t)edge * 16 + 4 * g) = make_float4(yv0, yv1, yv2, yv3);
}

extern "C" void kernel_launch(void* const* d_in, const int* in_sizes, int n_in,
                              void* d_out, int out_size, void* d_ws, size_t ws_size,
                              hipStream_t stream) {
    const float* x     = (const float*)d_in[0];
    const int*   ei    = (const int*)d_in[1];
    const float* ea    = (const float*)d_in[2];
    const float* Wg    = (const float*)d_in[3];
    const float* a_src = (const float*)d_in[4];
    const float* a_dst = (const float*)d_in[5];
    const float* b_gat = (const float*)d_in[6];
    const float* W1    = (const float*)d_in[7];
    const float* b1    = (const float*)d_in[8];
    const float* W2    = (const float*)d_in[9];
    const float* b2    = (const float*)d_in[10];
    const float* W3    = (const float*)d_in[11];
    const float* b3    = (const float*)d_in[12];

    float* ws  = (float*)d_ws;
    float* h   = ws + OFF_H;
    float* hs  = ws + OFF_HS;
    float* hd  = ws + OFF_HD;
    float* den = ws + OFF_DEN;
    float* xg  = ws + OFF_XG;
    uint32_t* img = (uint32_t*)(ws + OFF_IMG);

    prep_kernel<<<1, 64, 0, stream>>>(W1, b1, W2, b2, W3, b3, img);
    node_kernel<<<(NN + 255) / 256, 256, 0, stream>>>(x, Wg, a_src, a_dst,
                                                      h, hs, hd, den, xg);
    int ne_tot = NE + NN;
    edge_kernel<<<(ne_tot + 255) / 256, 256, 0, stream>>>(ei, hs, hd, h, den, xg);
    div_kernel<<<(NN + 255) / 256, 256, 0, stream>>>(xg, den, b_gat);
    rk4_kernel<<<NE / 64, 256, 0, stream>>>(ei, ea, xg, img, (float*)d_out);
}

// Round 11
// 1097.644 us; speedup vs baseline: 1.4322x; 1.0124x over previous
//
#include <hip/hip_runtime.h>
#include <math.h>
#include <stdint.h>

#define NN 100000
#define NE 1600000
#define IN_DIM 128
#define HID 64
#define EDIM 16
#define NEG_SLOPE 0.2f

// ws layout (float offsets)
#define OFF_H    0          // NN*4
#define OFF_HS   400000     // NN
#define OFF_HD   500000     // NN
#define OFF_DEN  600000     // NN
#define OFF_XG   700000     // NN*4
#define OFF_IMG  2800000    // 19*256 u32 = 4864

typedef __attribute__((ext_vector_type(8))) short bf16x8;
typedef __attribute__((ext_vector_type(4))) float f32x4;
typedef __attribute__((ext_vector_type(2))) float f32x2;
typedef __attribute__((ext_vector_type(2))) __bf16 bf16x2;

#define MFMA16(A, B, C) __builtin_amdgcn_mfma_f32_16x16x32_bf16((A), (B), (C), 0, 0, 0)

__device__ inline bf16x8 as_bf(uint4 x) { union { uint4 a; bf16x8 b; } u; u.a = x; return u.b; }
__device__ inline f32x4 as_f4(uint4 x) { union { uint4 a; f32x4 f; } u; u.a = x; return u.f; }

// packed f32x2 -> bf16x2 via LLVM fptrunc (validated r10: big win, RNE)
__device__ inline uint32_t pk2(float lo, float hi) {
    f32x2 v; v.x = lo; v.y = hi;
    bf16x2 b = __builtin_convertvector(v, bf16x2);
    union { bf16x2 b; uint32_t u; } uu; uu.b = b; return uu.u;
}

// prep-side RNE pack (cold path)
__device__ inline uint16_t f2bf_rne(float f) {
    uint32_t x = __float_as_uint(f);
    uint32_t r = x + 0x7FFFu + ((x >> 16) & 1u);
    return (uint16_t)(r >> 16);
}
__device__ inline uint32_t pk2c(float lo, float hi) {
    return (uint32_t)f2bf_rne(lo) | ((uint32_t)f2bf_rne(hi) << 16);
}

// ---------------- GAT conv (validated r9/r10) ----------------
__global__ void node_kernel(const float* __restrict__ x, const float* __restrict__ Wg,
                            const float* __restrict__ a_src, const float* __restrict__ a_dst,
                            float* __restrict__ h, float* __restrict__ hs,
                            float* __restrict__ hd, float* __restrict__ den,
                            float* __restrict__ xg) {
    int i = blockIdx.x * blockDim.x + threadIdx.x;
    if (i >= NN) return;
    float acc0 = 0.f, acc1 = 0.f, acc2 = 0.f, acc3 = 0.f;
    const float* xr = x + (size_t)i * IN_DIM;
#pragma unroll
    for (int d = 0; d < IN_DIM; d += 4) {
        float4 xv = *(const float4*)(xr + d);
        acc0 = fmaf(xv.x, Wg[(d + 0) * 4 + 0], acc0);
        acc1 = fmaf(xv.x, Wg[(d + 0) * 4 + 1], acc1);
        acc2 = fmaf(xv.x, Wg[(d + 0) * 4 + 2], acc2);
        acc3 = fmaf(xv.x, Wg[(d + 0) * 4 + 3], acc3);
        acc0 = fmaf(xv.y, Wg[(d + 1) * 4 + 0], acc0);
        acc1 = fmaf(xv.y, Wg[(d + 1) * 4 + 1], acc1);
        acc2 = fmaf(xv.y, Wg[(d + 1) * 4 + 2], acc2);
        acc3 = fmaf(xv.y, Wg[(d + 1) * 4 + 3], acc3);
        acc0 = fmaf(xv.z, Wg[(d + 2) * 4 + 0], acc0);
        acc1 = fmaf(xv.z, Wg[(d + 2) * 4 + 1], acc1);
        acc2 = fmaf(xv.z, Wg[(d + 2) * 4 + 2], acc2);
        acc3 = fmaf(xv.z, Wg[(d + 2) * 4 + 3], acc3);
        acc0 = fmaf(xv.w, Wg[(d + 3) * 4 + 0], acc0);
        acc1 = fmaf(xv.w, Wg[(d + 3) * 4 + 1], acc1);
        acc2 = fmaf(xv.w, Wg[(d + 3) * 4 + 2], acc2);
        acc3 = fmaf(xv.w, Wg[(d + 3) * 4 + 3], acc3);
    }
    *(float4*)(h + (size_t)i * 4) = make_float4(acc0, acc1, acc2, acc3);
    hs[i] = acc0 * a_src[0] + acc1 * a_src[1] + acc2 * a_src[2] + acc3 * a_src[3];
    hd[i] = acc0 * a_dst[0] + acc1 * a_dst[1] + acc2 * a_dst[2] + acc3 * a_dst[3];
    den[i] = 0.f;
    *(float4*)(xg + (size_t)i * 4) = make_float4(0.f, 0.f, 0.f, 0.f);
}

__global__ void edge_kernel(const int* __restrict__ ei, const float* __restrict__ hs,
                            const float* __restrict__ hd, const float* __restrict__ h,
                            float* __restrict__ den, float* __restrict__ xg) {
    int e = blockIdx.x * blockDim.x + threadIdx.x;
    if (e >= NE + NN) return;
    int r, c;
    if (e < NE) { r = ei[e]; c = ei[NE + e]; }
    else { r = e - NE; c = r; }
    float v = hs[r] + hd[c];
    v = (v >= 0.f) ? v : NEG_SLOPE * v;
    float pe = expf(v);
    float4 hv = *(const float4*)(h + (size_t)r * 4);
    atomicAdd(&den[c], pe);
    atomicAdd(&xg[4 * c + 0], pe * hv.x);
    atomicAdd(&xg[4 * c + 1], pe * hv.y);
    atomicAdd(&xg[4 * c + 2], pe * hv.z);
    atomicAdd(&xg[4 * c + 3], pe * hv.w);
}

__global__ void div_kernel(float* __restrict__ xg, const float* __restrict__ den,
                           const float* __restrict__ b_gat) {
    int i = blockIdx.x * blockDim.x + threadIdx.x;
    if (i >= NN) return;
    float inv = 1.0f / den[i];
    float4 n = *(const float4*)(xg + (size_t)i * 4);
    *(float4*)(xg + (size_t)i * 4) =
        make_float4(fmaf(n.x, inv, b_gat[0]), fmaf(n.y, inv, b_gat[1]),
                    fmaf(n.z, inv, b_gat[2]), fmaf(n.w, inv, b_gat[3]));
}

// ---------------- fragment image prep (PERMUTED layout, validated r8-r10) ----------------
// Hidden-unit relabeling u(q,g,r) = 32*(q&1) + 8*g + 4*(q>>1) + r makes D-slot
// order == next layer's B k-order => zero cross-lane movement between layers.
// Layer-1 B per lane g: j=0..3 -> y[4g+j]; j=4,5 -> f[2g],f[2g+1];
// j=6 (g==0 only) -> bias-one; j=7 -> zero.
__global__ void prep_kernel(const float* __restrict__ W1, const float* __restrict__ b1,
                            const float* __restrict__ W2, const float* __restrict__ b2,
                            const float* __restrict__ W3, const float* __restrict__ b3,
                            uint32_t* __restrict__ img) {
    int l = threadIdx.x;
    if (l >= 64) return;
    int e = l & 15, g = l >> 4;
    int er = e & 3, eq = e >> 2;
    for (int q = 0; q < 4; ++q) {
        int u = 32 * (q & 1) + 8 * eq + 4 * (q >> 1) + er;
        img[q * 256 + l * 4 + 0] = pk2c(W1[(8 + 4 * g + 0) * 64 + u], W1[(8 + 4 * g + 1) * 64 + u]);
        img[q * 256 + l * 4 + 1] = pk2c(W1[(8 + 4 * g + 2) * 64 + u], W1[(8 + 4 * g + 3) * 64 + u]);
        img[q * 256 + l * 4 + 2] = pk2c(W1[(2 * g + 0) * 64 + u], W1[(2 * g + 1) * 64 + u]);
        img[q * 256 + l * 4 + 3] = pk2c((g == 0) ? b1[u] : 0.f, 0.f);
    }
    for (int t = 0; t < 2; ++t)
        for (int q = 0; q < 4; ++q) {
            int u = 32 * (q & 1) + 8 * eq + 4 * (q >> 1) + er;
            for (int j2 = 0; j2 < 4; ++j2) {
                int k0 = 32 * t + 8 * g + 2 * j2;
                img[(4 + t * 4 + q) * 256 + l * 4 + j2] =
                    pk2c(W2[k0 * 64 + u], W2[(k0 + 1) * 64 + u]);
            }
        }
    for (int t = 0; t < 2; ++t)
        for (int j2 = 0; j2 < 4; ++j2) {
            int k0 = 32 * t + 8 * g + 2 * j2;
            img[(12 + t) * 256 + l * 4 + j2] =
                pk2c(W3[k0 * 16 + e], W3[(k0 + 1) * 16 + e]);
        }
    for (int q = 0; q < 4; ++q)
        for (int r = 0; r < 4; ++r)
            img[(14 + q) * 256 + l * 4 + r] =
                __float_as_uint(b2[32 * (q & 1) + 8 * g + 4 * (q >> 1) + r]);
    for (int r = 0; r < 4; ++r)
        img[18 * 256 + l * 4 + r] = __float_as_uint(b3[4 * g + r]);
}

// ---------------- RK4 edge MLP: dual 16-edge groups per wave (r11) ----------------
// Two independent RK4 streams per wave -> 2x independent MFMAs per scheduling
// region + 6 effective streams/SIMD at 3 waves; fills the ~22% neither-pipe-
// issues gap seen in r10. Weights/biases shared across groups.
__global__ __launch_bounds__(256, 3) void rk4_kernel(
    const int* __restrict__ ei, const float* __restrict__ ea,
    const float* __restrict__ xg, const uint32_t* __restrict__ img,
    float* __restrict__ out) {
    const int tid = threadIdx.x;
    const int w = tid >> 6, l = tid & 63;
    const int e = l & 15, g = l >> 4;
    const int eA = blockIdx.x * 128 + w * 32 + e;
    const int eB = eA + 16;

    uint4 F[19];
#pragma unroll
    for (int i = 0; i < 19; ++i) F[i] = *(const uint4*)(img + i * 256 + l * 4);

    const bf16x8 W1f0 = as_bf(F[0]), W1f1 = as_bf(F[1]), W1f2 = as_bf(F[2]), W1f3 = as_bf(F[3]);
    const bf16x8 W2f00 = as_bf(F[4]), W2f01 = as_bf(F[5]), W2f02 = as_bf(F[6]), W2f03 = as_bf(F[7]);
    const bf16x8 W2f10 = as_bf(F[8]), W2f11 = as_bf(F[9]), W2f12 = as_bf(F[10]), W2f13 = as_bf(F[11]);
    const bf16x8 W3f0 = as_bf(F[12]), W3f1 = as_bf(F[13]);
    const f32x4 b2f0 = as_f4(F[14]), b2f1 = as_f4(F[15]), b2f2 = as_f4(F[16]), b2f3 = as_f4(F[17]);
    const f32x4 b3f = as_f4(F[18]);

    uint32_t StfA, StfB;
    {
        int idxA = (g < 2) ? ei[eA] : ei[NE + eA];
        int idxB = (g < 2) ? ei[eB] : ei[NE + eB];
        const float2 fvA = *(const float2*)(xg + (size_t)idxA * 4 + ((2 * g) & 3));
        const float2 fvB = *(const float2*)(xg + (size_t)idxB * 4 + ((2 * g) & 3));
        StfA = pk2(fvA.x, fvA.y);
        StfB = pk2(fvB.x, fvB.y);
    }
    const uint32_t Stb = (g == 0) ? 0x00003F80u : 0u;  // bf16(1.0) at k=6

    float4 yA4 = *(const float4*)(ea + (size_t)eA * 16 + 4 * g);
    float4 yB4 = *(const float4*)(ea + (size_t)eB * 16 + 4 * g);
    float yA0 = yA4.x, yA1 = yA4.y, yA2 = yA4.z, yA3 = yA4.w;
    float yB0 = yB4.x, yB1 = yB4.y, yB2 = yB4.z, yB3 = yB4.w;

    const f32x4 zero4 = {0.f, 0.f, 0.f, 0.f};
    const float dt6 = 0.125f / 6.0f;

    auto rhs2 = [&](float aA0, float aA1, float aA2, float aA3,
                    float aB0, float aB1, float aB2, float aB3,
                    f32x4& kkA, f32x4& kkB) {
        uint4 bA, bB;
        bA.x = pk2(aA0, aA1); bA.y = pk2(aA2, aA3); bA.z = StfA; bA.w = Stb;
        bB.x = pk2(aB0, aB1); bB.y = pk2(aB2, aB3); bB.z = StfB; bB.w = Stb;
        bf16x8 B1A = as_bf(bA), B1B = as_bf(bB);
        f32x4 hA0 = MFMA16(W1f0, B1A, zero4);
        f32x4 hB0 = MFMA16(W1f0, B1B, zero4);
        f32x4 hA1 = MFMA16(W1f1, B1A, zero4);
        f32x4 hB1 = MFMA16(W1f1, B1B, zero4);
        f32x4 hA2 = MFMA16(W1f2, B1A, zero4);
        f32x4 hB2 = MFMA16(W1f2, B1B, zero4);
        f32x4 hA3 = MFMA16(W1f3, B1A, zero4);
        f32x4 hB3 = MFMA16(W1f3, B1B, zero4);
        uint4 qA0, qA1, qB0, qB1;
        qA0.x = pk2(fmaxf(hA0[0], 0.f), fmaxf(hA0[1], 0.f));
        qA0.y = pk2(fmaxf(hA0[2], 0.f), fmaxf(hA0[3], 0.f));
        qA0.z = pk2(fmaxf(hA2[0], 0.f), fmaxf(hA2[1], 0.f));
        qA0.w = pk2(fmaxf(hA2[2], 0.f), fmaxf(hA2[3], 0.f));
        qA1.x = pk2(fmaxf(hA1[0], 0.f), fmaxf(hA1[1], 0.f));
        qA1.y = pk2(fmaxf(hA1[2], 0.f), fmaxf(hA1[3], 0.f));
        qA1.z = pk2(fmaxf(hA3[0], 0.f), fmaxf(hA3[1], 0.f));
        qA1.w = pk2(fmaxf(hA3[2], 0.f), fmaxf(hA3[3], 0.f));
        qB0.x = pk2(fmaxf(hB0[0], 0.f), fmaxf(hB0[1], 0.f));
        qB0.y = pk2(fmaxf(hB0[2], 0.f), fmaxf(hB0[3], 0.f));
        qB0.z = pk2(fmaxf(hB2[0], 0.f), fmaxf(hB2[1], 0.f));
        qB0.w = pk2(fmaxf(hB2[2], 0.f), fmaxf(hB2[3], 0.f));
        qB1.x = pk2(fmaxf(hB1[0], 0.f), fmaxf(hB1[1], 0.f));
        qB1.y = pk2(fmaxf(hB1[2], 0.f), fmaxf(hB1[3], 0.f));
        qB1.z = pk2(fmaxf(hB3[0], 0.f), fmaxf(hB3[1], 0.f));
        qB1.w = pk2(fmaxf(hB3[2], 0.f), fmaxf(hB3[3], 0.f));
        bf16x8 B20A = as_bf(qA0), B21A = as_bf(qA1);
        bf16x8 B20B = as_bf(qB0), B21B = as_bf(qB1);
        f32x4 pA0 = MFMA16(W2f00, B20A, b2f0); pA0 = MFMA16(W2f10, B21A, pA0);
        f32x4 pB0 = MFMA16(W2f00, B20B, b2f0); pB0 = MFMA16(W2f10, B21B, pB0);
        f32x4 pA1 = MFMA16(W2f01, B20A, b2f1); pA1 = MFMA16(W2f11, B21A, pA1);
        f32x4 pB1 = MFMA16(W2f01, B20B, b2f1); pB1 = MFMA16(W2f11, B21B, pB1);
        f32x4 pA2 = MFMA16(W2f02, B20A, b2f2); pA2 = MFMA16(W2f12, B21A, pA2);
        f32x4 pB2 = MFMA16(W2f02, B20B, b2f2); pB2 = MFMA16(W2f12, B21B, pB2);
        f32x4 pA3 = MFMA16(W2f03, B20A, b2f3); pA3 = MFMA16(W2f13, B21A, pA3);
        f32x4 pB3 = MFMA16(W2f03, B20B, b2f3); pB3 = MFMA16(W2f13, B21B, pB3);
        uint4 rA0, rA1, rB0, rB1;
        rA0.x = pk2(fmaxf(pA0[0], 0.f), fmaxf(pA0[1], 0.f));
        rA0.y = pk2(fmaxf(pA0[2], 0.f), fmaxf(pA0[3], 0.f));
        rA0.z = pk2(fmaxf(pA2[0], 0.f), fmaxf(pA2[1], 0.f));
        rA0.w = pk2(fmaxf(pA2[2], 0.f), fmaxf(pA2[3], 0.f));
        rA1.x = pk2(fmaxf(pA1[0], 0.f), fmaxf(pA1[1], 0.f));
        rA1.y = pk2(fmaxf(pA1[2], 0.f), fmaxf(pA1[3], 0.f));
        rA1.z = pk2(fmaxf(pA3[0], 0.f), fmaxf(pA3[1], 0.f));
        rA1.w = pk2(fmaxf(pA3[2], 0.f), fmaxf(pA3[3], 0.f));
        rB0.x = pk2(fmaxf(pB0[0], 0.f), fmaxf(pB0[1], 0.f));
        rB0.y = pk2(fmaxf(pB0[2], 0.f), fmaxf(pB0[3], 0.f));
        rB0.z = pk2(fmaxf(pB2[0], 0.f), fmaxf(pB2[1], 0.f));
        rB0.w = pk2(fmaxf(pB2[2], 0.f), fmaxf(pB2[3], 0.f));
        rB1.x = pk2(fmaxf(pB1[0], 0.f), fmaxf(pB1[1], 0.f));
        rB1.y = pk2(fmaxf(pB1[2], 0.f), fmaxf(pB1[3], 0.f));
        rB1.z = pk2(fmaxf(pB3[0], 0.f), fmaxf(pB3[1], 0.f));
        rB1.w = pk2(fmaxf(pB3[2], 0.f), fmaxf(pB3[3], 0.f));
        bf16x8 B30A = as_bf(rA0), B31A = as_bf(rA1);
        bf16x8 B30B = as_bf(rB0), B31B = as_bf(rB1);
        f32x4 kA = MFMA16(W3f0, B30A, b3f);
        f32x4 kB = MFMA16(W3f0, B30B, b3f);
        kA = MFMA16(W3f1, B31A, kA);
        kB = MFMA16(W3f1, B31B, kB);
        kkA = kA; kkB = kB;
    };

#pragma unroll 1
    for (int step = 0; step < 8; ++step) {
        float aA0 = yA0, aA1 = yA1, aA2 = yA2, aA3 = yA3;
        float aB0 = yB0, aB1 = yB1, aB2 = yB2, aB3 = yB3;
        float cA0 = 0.f, cA1 = 0.f, cA2 = 0.f, cA3 = 0.f;
        float cB0 = 0.f, cB1 = 0.f, cB2 = 0.f, cB3 = 0.f;
#pragma unroll 1
        for (int s = 0; s < 4; ++s) {
            f32x4 kkA, kkB;
            rhs2(aA0, aA1, aA2, aA3, aB0, aB1, aB2, aB3, kkA, kkB);
            float wk = (s == 1 || s == 2) ? 2.f : 1.f;
            float cs = (s < 2) ? 0.0625f : (s == 2) ? 0.125f : 0.f;
            cA0 = fmaf(wk, kkA[0], cA0); cA1 = fmaf(wk, kkA[1], cA1);
            cA2 = fmaf(wk, kkA[2], cA2); cA3 = fmaf(wk, kkA[3], cA3);
            cB0 = fmaf(wk, kkB[0], cB0); cB1 = fmaf(wk, kkB[1], cB1);
            cB2 = fmaf(wk, kkB[2], cB2); cB3 = fmaf(wk, kkB[3], cB3);
            aA0 = fmaf(cs, kkA[0], yA0); aA1 = fmaf(cs, kkA[1], yA1);
            aA2 = fmaf(cs, kkA[2], yA2); aA3 = fmaf(cs, kkA[3], yA3);
            aB0 = fmaf(cs, kkB[0], yB0); aB1 = fmaf(cs, kkB[1], yB1);
            aB2 = fmaf(cs, kkB[2], yB2); aB3 = fmaf(cs, kkB[3], yB3);
        }
        yA0 = fmaf(dt6, cA0, yA0); yA1 = fmaf(dt6, cA1, yA1);
        yA2 = fmaf(dt6, cA2, yA2); yA3 = fmaf(dt6, cA3, yA3);
        yB0 = fmaf(dt6, cB0, yB0); yB1 = fmaf(dt6, cB1, yB1);
        yB2 = fmaf(dt6, cB2, yB2); yB3 = fmaf(dt6, cB3, yB3);
    }

    *(float4*)(out + (size_t)eA * 16 + 4 * g) = make_float4(yA0, yA1, yA2, yA3);
    *(float4*)(out + (size_t)eB * 16 + 4 * g) = make_float4(yB0, yB1, yB2, yB3);
}

extern "C" void kernel_launch(void* const* d_in, const int* in_sizes, int n_in,
                              void* d_out, int out_size, void* d_ws, size_t ws_size,
                              hipStream_t stream) {
    const float* x     = (const float*)d_in[0];
    const int*   ei    = (const int*)d_in[1];
    const float* ea    = (const float*)d_in[2];
    const float* Wg    = (const float*)d_in[3];
    const float* a_src = (const float*)d_in[4];
    const float* a_dst = (const float*)d_in[5];
    const float* b_gat = (const float*)d_in[6];
    const float* W1    = (const float*)d_in[7];
    const float* b1    = (const float*)d_in[8];
    const float* W2    = (const float*)d_in[9];
    const float* b2    = (const float*)d_in[10];
    const float* W3    = (const float*)d_in[11];
    const float* b3    = (const float*)d_in[12];

    float* ws  = (float*)d_ws;
    float* h   = ws + OFF_H;
    float* hs  = ws + OFF_HS;
    float* hd  = ws + OFF_HD;
    float* den = ws + OFF_DEN;
    float* xg  = ws + OFF_XG;
    uint32_t* img = (uint32_t*)(ws + OFF_IMG);

    prep_kernel<<<1, 64, 0, stream>>>(W1, b1, W2, b2, W3, b3, img);
    node_kernel<<<(NN + 255) / 256, 256, 0, stream>>>(x, Wg, a_src, a_dst,
                                                      h, hs, hd, den, xg);
    int ne_tot = NE + NN;
    edge_kernel<<<(ne_tot + 255) / 256, 256, 0, stream>>>(ei, hs, hd, h, den, xg);
    div_kernel<<<(NN + 255) / 256, 256, 0, stream>>>(xg, den, b_gat);
    rk4_kernel<<<NE / 128, 256, 0, stream>>>(ei, ea, xg, img, (float*)d_out);
}

// Round 12
// 936.045 us; speedup vs baseline: 1.6794x; 1.1726x over previous
//
#include <hip/hip_runtime.h>
#include <math.h>
#include <stdint.h>

#define NN 100000
#define NE 1600000
#define IN_DIM 128
#define HID 64
#define EDIM 16
#define NEG_SLOPE 0.2f

// ws layout (float offsets)
#define OFF_H    0          // NN*4
#define OFF_HS   400000     // NN
#define OFF_HD   500000     // NN
#define OFF_DEN  600000     // NN
#define OFF_XG   700000     // NN*4
#define OFF_IMG  2800000    // 19*256 u32 = 4864

typedef __attribute__((ext_vector_type(8))) short bf16x8;
typedef __attribute__((ext_vector_type(4))) float f32x4;
typedef __attribute__((ext_vector_type(2))) float f32x2;
typedef __attribute__((ext_vector_type(2))) __bf16 bf16x2;
typedef __attribute__((ext_vector_type(2))) short s16x2;

#define MFMA16(A, B, C) __builtin_amdgcn_mfma_f32_16x16x32_bf16((A), (B), (C), 0, 0, 0)

__device__ inline bf16x8 as_bf(uint4 x) { union { uint4 a; bf16x8 b; } u; u.a = x; return u.b; }
__device__ inline f32x4 as_f4(uint4 x) { union { uint4 a; f32x4 f; } u; u.a = x; return u.f; }

// packed f32x2 -> bf16x2 via LLVM fptrunc (validated r10, lowers to v_cvt_pk_bf16_f32)
__device__ inline uint32_t pk2(float lo, float hi) {
    f32x2 v; v.x = lo; v.y = hi;
    bf16x2 b = __builtin_convertvector(v, bf16x2);
    union { bf16x2 b; uint32_t u; } uu; uu.b = b; return uu.u;
}

// convert + packed relu: bf16 is sign-magnitude, so smax(as_i16(x), 0) == relu
// exactly (negatives -> +0, positives unchanged; rounding order irrelevant since
// cvt is monotone & sign-preserving). Lowers to v_cvt_pk + v_pk_max_i16:
// 2 VALU/pair vs 3 for fmax-then-cvt. Compiler-generated (no asm) => hazards ok.
__device__ inline uint32_t pk2r(float lo, float hi) {
    f32x2 v; v.x = lo; v.y = hi;
    bf16x2 b = __builtin_convertvector(v, bf16x2);
    union { bf16x2 b; s16x2 s; uint32_t u; } uu; uu.b = b;
    s16x2 z = {0, 0};
    uu.s = __builtin_elementwise_max(uu.s, z);
    return uu.u;
}

// prep-side RNE pack (cold path)
__device__ inline uint16_t f2bf_rne(float f) {
    uint32_t x = __float_as_uint(f);
    uint32_t r = x + 0x7FFFu + ((x >> 16) & 1u);
    return (uint16_t)(r >> 16);
}
__device__ inline uint32_t pk2c(float lo, float hi) {
    return (uint32_t)f2bf_rne(lo) | ((uint32_t)f2bf_rne(hi) << 16);
}

// ---------------- GAT conv (validated r9-r11) ----------------
__global__ void node_kernel(const float* __restrict__ x, const float* __restrict__ Wg,
                            const float* __restrict__ a_src, const float* __restrict__ a_dst,
                            float* __restrict__ h, float* __restrict__ hs,
                            float* __restrict__ hd, float* __restrict__ den,
                            float* __restrict__ xg) {
    int i = blockIdx.x * blockDim.x + threadIdx.x;
    if (i >= NN) return;
    float acc0 = 0.f, acc1 = 0.f, acc2 = 0.f, acc3 = 0.f;
    const float* xr = x + (size_t)i * IN_DIM;
#pragma unroll
    for (int d = 0; d < IN_DIM; d += 4) {
        float4 xv = *(const float4*)(xr + d);
        acc0 = fmaf(xv.x, Wg[(d + 0) * 4 + 0], acc0);
        acc1 = fmaf(xv.x, Wg[(d + 0) * 4 + 1], acc1);
        acc2 = fmaf(xv.x, Wg[(d + 0) * 4 + 2], acc2);
        acc3 = fmaf(xv.x, Wg[(d + 0) * 4 + 3], acc3);
        acc0 = fmaf(xv.y, Wg[(d + 1) * 4 + 0], acc0);
        acc1 = fmaf(xv.y, Wg[(d + 1) * 4 + 1], acc1);
        acc2 = fmaf(xv.y, Wg[(d + 1) * 4 + 2], acc2);
        acc3 = fmaf(xv.y, Wg[(d + 1) * 4 + 3], acc3);
        acc0 = fmaf(xv.z, Wg[(d + 2) * 4 + 0], acc0);
        acc1 = fmaf(xv.z, Wg[(d + 2) * 4 + 1], acc1);
        acc2 = fmaf(xv.z, Wg[(d + 2) * 4 + 2], acc2);
        acc3 = fmaf(xv.z, Wg[(d + 2) * 4 + 3], acc3);
        acc0 = fmaf(xv.w, Wg[(d + 3) * 4 + 0], acc0);
        acc1 = fmaf(xv.w, Wg[(d + 3) * 4 + 1], acc1);
        acc2 = fmaf(xv.w, Wg[(d + 3) * 4 + 2], acc2);
        acc3 = fmaf(xv.w, Wg[(d + 3) * 4 + 3], acc3);
    }
    *(float4*)(h + (size_t)i * 4) = make_float4(acc0, acc1, acc2, acc3);
    hs[i] = acc0 * a_src[0] + acc1 * a_src[1] + acc2 * a_src[2] + acc3 * a_src[3];
    hd[i] = acc0 * a_dst[0] + acc1 * a_dst[1] + acc2 * a_dst[2] + acc3 * a_dst[3];
    den[i] = 0.f;
    *(float4*)(xg + (size_t)i * 4) = make_float4(0.f, 0.f, 0.f, 0.f);
}

__global__ void edge_kernel(const int* __restrict__ ei, const float* __restrict__ hs,
                            const float* __restrict__ hd, const float* __restrict__ h,
                            float* __restrict__ den, float* __restrict__ xg) {
    int e = blockIdx.x * blockDim.x + threadIdx.x;
    if (e >= NE + NN) return;
    int r, c;
    if (e < NE) { r = ei[e]; c = ei[NE + e]; }
    else { r = e - NE; c = r; }
    float v = hs[r] + hd[c];
    v = (v >= 0.f) ? v : NEG_SLOPE * v;
    float pe = expf(v);
    float4 hv = *(const float4*)(h + (size_t)r * 4);
    atomicAdd(&den[c], pe);
    atomicAdd(&xg[4 * c + 0], pe * hv.x);
    atomicAdd(&xg[4 * c + 1], pe * hv.y);
    atomicAdd(&xg[4 * c + 2], pe * hv.z);
    atomicAdd(&xg[4 * c + 3], pe * hv.w);
}

__global__ void div_kernel(float* __restrict__ xg, const float* __restrict__ den,
                           const float* __restrict__ b_gat) {
    int i = blockIdx.x * blockDim.x + threadIdx.x;
    if (i >= NN) return;
    float inv = 1.0f / den[i];
    float4 n = *(const float4*)(xg + (size_t)i * 4);
    *(float4*)(xg + (size_t)i * 4) =
        make_float4(fmaf(n.x, inv, b_gat[0]), fmaf(n.y, inv, b_gat[1]),
                    fmaf(n.z, inv, b_gat[2]), fmaf(n.w, inv, b_gat[3]));
}

// ---------------- fragment image prep (PERMUTED layout, validated r8-r11) ----------------
// Hidden-unit relabeling u(q,g,r) = 32*(q&1) + 8*g + 4*(q>>1) + r makes D-slot
// order == next layer's B k-order => zero cross-lane movement between layers.
// Layer-1 B per lane g: j=0..3 -> y[4g+j]; j=4,5 -> f[2g],f[2g+1];
// j=6 (g==0 only) -> bias-one; j=7 -> zero.
__global__ void prep_kernel(const float* __restrict__ W1, const float* __restrict__ b1,
                            const float* __restrict__ W2, const float* __restrict__ b2,
                            const float* __restrict__ W3, const float* __restrict__ b3,
                            uint32_t* __restrict__ img) {
    int l = threadIdx.x;
    if (l >= 64) return;
    int e = l & 15, g = l >> 4;
    int er = e & 3, eq = e >> 2;
    for (int q = 0; q < 4; ++q) {
        int u = 32 * (q & 1) + 8 * eq + 4 * (q >> 1) + er;
        img[q * 256 + l * 4 + 0] = pk2c(W1[(8 + 4 * g + 0) * 64 + u], W1[(8 + 4 * g + 1) * 64 + u]);
        img[q * 256 + l * 4 + 1] = pk2c(W1[(8 + 4 * g + 2) * 64 + u], W1[(8 + 4 * g + 3) * 64 + u]);
        img[q * 256 + l * 4 + 2] = pk2c(W1[(2 * g + 0) * 64 + u], W1[(2 * g + 1) * 64 + u]);
        img[q * 256 + l * 4 + 3] = pk2c((g == 0) ? b1[u] : 0.f, 0.f);
    }
    for (int t = 0; t < 2; ++t)
        for (int q = 0; q < 4; ++q) {
            int u = 32 * (q & 1) + 8 * eq + 4 * (q >> 1) + er;
            for (int j2 = 0; j2 < 4; ++j2) {
                int k0 = 32 * t + 8 * g + 2 * j2;
                img[(4 + t * 4 + q) * 256 + l * 4 + j2] =
                    pk2c(W2[k0 * 64 + u], W2[(k0 + 1) * 64 + u]);
            }
        }
    for (int t = 0; t < 2; ++t)
        for (int j2 = 0; j2 < 4; ++j2) {
            int k0 = 32 * t + 8 * g + 2 * j2;
            img[(12 + t) * 256 + l * 4 + j2] =
                pk2c(W3[k0 * 16 + e], W3[(k0 + 1) * 16 + e]);
        }
    for (int q = 0; q < 4; ++q)
        for (int r = 0; r < 4; ++r)
            img[(14 + q) * 256 + l * 4 + r] =
                __float_as_uint(b2[32 * (q & 1) + 8 * g + 4 * (q >> 1) + r]);
    for (int r = 0; r < 4; ++r)
        img[18 * 256 + l * 4 + r] = __float_as_uint(b3[4 * g + r]);
}

// ---------------- RK4 edge MLP (r12): single-stream, pk_max relu, 4-wave aim ----------------
__global__ __launch_bounds__(256, 4) void rk4_kernel(
    const int* __restrict__ ei, const float* __restrict__ ea,
    const float* __restrict__ xg, const uint32_t* __restrict__ img,
    float* __restrict__ out) {
    const int tid = threadIdx.x;
    const int w = tid >> 6, l = tid & 63;
    const int e = l & 15, g = l >> 4;
    const int edge = blockIdx.x * 64 + w * 16 + e;

    uint4 F[19];
#pragma unroll
    for (int i = 0; i < 19; ++i) F[i] = *(const uint4*)(img + i * 256 + l * 4);

    const bf16x8 W1f0 = as_bf(F[0]), W1f1 = as_bf(F[1]), W1f2 = as_bf(F[2]), W1f3 = as_bf(F[3]);
    const bf16x8 W2f00 = as_bf(F[4]), W2f01 = as_bf(F[5]), W2f02 = as_bf(F[6]), W2f03 = as_bf(F[7]);
    const bf16x8 W2f10 = as_bf(F[8]), W2f11 = as_bf(F[9]), W2f12 = as_bf(F[10]), W2f13 = as_bf(F[11]);
    const bf16x8 W3f0 = as_bf(F[12]), W3f1 = as_bf(F[13]);
    const f32x4 b2f0 = as_f4(F[14]), b2f1 = as_f4(F[15]), b2f2 = as_f4(F[16]), b2f3 = as_f4(F[17]);
    const f32x4 b3f = as_f4(F[18]);

    uint32_t Stf, Stb;
    {
        int idx = (g < 2) ? ei[edge] : ei[NE + edge];
        const float2 fv = *(const float2*)(xg + (size_t)idx * 4 + ((2 * g) & 3));
        Stf = pk2(fv.x, fv.y);
        Stb = (g == 0) ? 0x00003F80u : 0u;  // bf16(1.0) at k=6
    }

    float4 y4 = *(const float4*)(ea + (size_t)edge * 16 + 4 * g);
    float yv0 = y4.x, yv1 = y4.y, yv2 = y4.z, yv3 = y4.w;

    const f32x4 zero4 = {0.f, 0.f, 0.f, 0.f};
    const float dt6 = 0.125f / 6.0f;

    auto rhs = [&](float a0, float a1, float a2, float a3) -> f32x4 {
        uint4 bb;
        bb.x = pk2(a0, a1); bb.y = pk2(a2, a3); bb.z = Stf; bb.w = Stb;
        bf16x8 B1 = as_bf(bb);
        f32x4 h0 = MFMA16(W1f0, B1, zero4);
        f32x4 h1 = MFMA16(W1f1, B1, zero4);
        f32x4 h2 = MFMA16(W1f2, B1, zero4);
        f32x4 h3 = MFMA16(W1f3, B1, zero4);
        uint4 q20, q21;
        q20.x = pk2r(h0[0], h0[1]);
        q20.y = pk2r(h0[2], h0[3]);
        q20.z = pk2r(h2[0], h2[1]);
        q20.w = pk2r(h2[2], h2[3]);
        q21.x = pk2r(h1[0], h1[1]);
        q21.y = pk2r(h1[2], h1[3]);
        q21.z = pk2r(h3[0], h3[1]);
        q21.w = pk2r(h3[2], h3[3]);
        bf16x8 B20 = as_bf(q20), B21 = as_bf(q21);
        f32x4 p0 = MFMA16(W2f00, B20, b2f0); p0 = MFMA16(W2f10, B21, p0);
        f32x4 p1 = MFMA16(W2f01, B20, b2f1); p1 = MFMA16(W2f11, B21, p1);
        f32x4 p2 = MFMA16(W2f02, B20, b2f2); p2 = MFMA16(W2f12, B21, p2);
        f32x4 p3 = MFMA16(W2f03, B20, b2f3); p3 = MFMA16(W2f13, B21, p3);
        uint4 q30, q31;
        q30.x = pk2r(p0[0], p0[1]);
        q30.y = pk2r(p0[2], p0[3]);
        q30.z = pk2r(p2[0], p2[1]);
        q30.w = pk2r(p2[2], p2[3]);
        q31.x = pk2r(p1[0], p1[1]);
        q31.y = pk2r(p1[2], p1[3]);
        q31.z = pk2r(p3[0], p3[1]);
        q31.w = pk2r(p3[2], p3[3]);
        bf16x8 B30 = as_bf(q30), B31 = as_bf(q31);
        f32x4 kk = MFMA16(W3f0, B30, b3f);
        kk = MFMA16(W3f1, B31, kk);
        return kk;
    };

#pragma unroll 1
    for (int step = 0; step < 8; ++step) {
        float a0 = yv0, a1 = yv1, a2 = yv2, a3 = yv3;
        float c0 = 0.f, c1 = 0.f, c2 = 0.f, c3 = 0.f;
#pragma unroll 1
        for (int s = 0; s < 4; ++s) {
            f32x4 kk = rhs(a0, a1, a2, a3);
            float wk = (s == 1 || s == 2) ? 2.f : 1.f;
            float cs = (s < 2) ? 0.0625f : (s == 2) ? 0.125f : 0.f;
            c0 = fmaf(wk, kk[0], c0); c1 = fmaf(wk, kk[1], c1);
            c2 = fmaf(wk, kk[2], c2); c3 = fmaf(wk, kk[3], c3);
            a0 = fmaf(cs, kk[0], yv0); a1 = fmaf(cs, kk[1], yv1);
            a2 = fmaf(cs, kk[2], yv2); a3 = fmaf(cs, kk[3], yv3);
        }
        yv0 = fmaf(dt6, c0, yv0); yv1 = fmaf(dt6, c1, yv1);
        yv2 = fmaf(dt6, c2, yv2); yv3 = fmaf(dt6, c3, yv3);
    }

    *(float4*)(out + (size_t)edge * 16 + 4 * g) = make_float4(yv0, yv1, yv2, yv3);
}

extern "C" void kernel_launch(void* const* d_in, const int* in_sizes, int n_in,
                              void* d_out, int out_size, void* d_ws, size_t ws_size,
                              hipStream_t stream) {
    const float* x     = (const float*)d_in[0];
    const int*   ei    = (const int*)d_in[1];
    const float* ea    = (const float*)d_in[2];
    const float* Wg    = (const float*)d_in[3];
    const float* a_src = (const float*)d_in[4];
    const float* a_dst = (const float*)d_in[5];
    const float* b_gat = (const float*)d_in[6];
    const float* W1    = (const float*)d_in[7];
    const float* b1    = (const float*)d_in[8];
    const float* W2    = (const float*)d_in[9];
    const float* b2    = (const float*)d_in[10];
    const float* W3    = (const float*)d_in[11];
    const float* b3    = (const float*)d_in[12];

    float* ws  = (float*)d_ws;
    float* h   = ws + OFF_H;
    float* hs  = ws + OFF_HS;
    float* hd  = ws + OFF_HD;
    float* den = ws + OFF_DEN;
    float* xg  = ws + OFF_XG;
    uint32_t* img = (uint32_t*)(ws + OFF_IMG);

    prep_kernel<<<1, 64, 0, stream>>>(W1, b1, W2, b2, W3, b3, img);
    node_kernel<<<(NN + 255) / 256, 256, 0, stream>>>(x, Wg, a_src, a_dst,
                                                      h, hs, hd, den, xg);
    int ne_tot = NE + NN;
    edge_kernel<<<(ne_tot + 255) / 256, 256, 0, stream>>>(ei, hs, hd, h, den, xg);
    div_kernel<<<(NN + 255) / 256, 256, 0, stream>>>(xg, den, b_gat);
    rk4_kernel<<<NE / 64, 256, 0, stream>>>(ei, ea, xg, img, (float*)d_out);
}